// Round 7
// baseline (3961.701 us; speedup 1.0000x reference)
//
#include <hip/hip_runtime.h>
#include <cstdint>

#define N_PTS   8192
#define S_PTS   2048
#define K_SMP   32
#define BATCH   8
#define P_TOT   (BATCH*S_PTS*K_SMP)   /* 524288 */
#define R2      0.16f
#define CNT_INV (1.0f/524288.0f)

// Unfused: matches numpy-f32 elementwise square + sequential 3-sum. PROVEN r5/r6.
__device__ __forceinline__ float sqd(float ax, float ay, float az,
                                     float bx, float by, float bz) {
    float dx = __fsub_rn(ax, bx), dy = __fsub_rn(ay, by), dz = __fsub_rn(az, bz);
    return __fadd_rn(__fadd_rn(__fmul_rn(dx, dx), __fmul_rn(dy, dy)), __fmul_rn(dz, dz));
}

// ---------------------------------------------------------------- FPS v3
// 1024 thr (16 waves, 4/SIMD -> latency hiding) x 8 pts. Reduce:
//   per-thread (8-chain) -> DPP row_ror 1/2/4/8 (16-lane row, proven r6)
//   -> shfl_xor 16/32 (cross-row) -> 1 partial/wave -> wave0 second stage
//   (16 partials, 4-step u64 shfl_xor) -> LDS broadcast. Double-buffered
//   slots; 2 barriers/step. Key = bits(maxval)<<32 | ~idx (max val, min idx).
#define ROR_STEP(N)                                                                         \
    {                                                                                       \
        float ov = __int_as_float(__builtin_amdgcn_mov_dpp(__float_as_int(bv),              \
                                                           0x120|(N), 0xF, 0xF, true));     \
        int   oi = __builtin_amdgcn_mov_dpp(bi, 0x120|(N), 0xF, 0xF, true);                 \
        if (ov > bv || (ov == bv && oi < bi)) { bv = ov; bi = oi; }                         \
    }
#define XOR_STEP(N)                                                                         \
    {                                                                                       \
        float ov = __shfl_xor(bv, N);                                                       \
        int   oi = __shfl_xor(bi, N);                                                       \
        if (ov > bv || (ov == bv && oi < bi)) { bv = ov; bi = oi; }                         \
    }

__global__ __launch_bounds__(1024, 4) void fps_kernel(const float* __restrict__ xyz,
                                                      float* __restrict__ newxyz) {
    __shared__ float sx[N_PTS], sy[N_PTS], sz[N_PTS];      // 96 KiB (broadcast source)
    __shared__ unsigned long long s_part[2][16];           // per-wave partials, dbuf
    __shared__ unsigned long long s_best[2];               // final key, dbuf
    __shared__ int s_sel[S_PTS];                           // 8 KiB

    const int b = blockIdx.x, t = threadIdx.x;
    const int w = t >> 6, lane = t & 63;
    const float* xb = xyz + (size_t)b * 3 * N_PTS;
    const int base = t * 8;

    float px[8], py[8], pz[8], dist[8];
#pragma unroll
    for (int q = 0; q < 2; q++) {
        float4 vx = *(const float4*)(xb + base + 4 * q);
        float4 vy = *(const float4*)(xb + N_PTS + base + 4 * q);
        float4 vz = *(const float4*)(xb + 2 * N_PTS + base + 4 * q);
        px[4*q] = vx.x; px[4*q+1] = vx.y; px[4*q+2] = vx.z; px[4*q+3] = vx.w;
        py[4*q] = vy.x; py[4*q+1] = vy.y; py[4*q+2] = vy.z; py[4*q+3] = vy.w;
        pz[4*q] = vz.x; pz[4*q+1] = vz.y; pz[4*q+2] = vz.z; pz[4*q+3] = vz.w;
    }
#pragma unroll
    for (int j = 0; j < 8; j++) {
        sx[base+j] = px[j]; sy[base+j] = py[j]; sz[base+j] = pz[j];
        dist[j] = 1e10f;
    }
    if (t == 0) s_sel[0] = 0;
    __syncthreads();

    int last = 0;
    for (int i = 1; i < S_PTS; i++) {
        float lx = sx[last], ly = sy[last], lz = sz[last];   // LDS broadcast
        float bv = -1.0f; int bi = 0;
#pragma unroll
        for (int j = 0; j < 8; j++) {
            float d  = sqd(px[j], py[j], pz[j], lx, ly, lz);
            float nd = fminf(dist[j], d);
            dist[j] = nd;
            if (nd > bv) { bv = nd; bi = base + j; }   // strict > : first index wins
        }
        ROR_STEP(1) ROR_STEP(2) ROR_STEP(4) ROR_STEP(8)    // 16-lane row argmax
        XOR_STEP(16) XOR_STEP(32)                          // cross-row -> wave argmax
        if (lane == 0)
            s_part[i & 1][w] = ((unsigned long long)__float_as_uint(bv) << 32)
                             | (unsigned long long)(0xFFFFFFFFu - (unsigned)bi);
        __syncthreads();
        if (w == 0) {                                       // wave 0: 16 -> 1
            unsigned long long k = s_part[i & 1][lane & 15];
#pragma unroll
            for (int off = 1; off <= 8; off <<= 1) {
                unsigned long long ok = __shfl_xor(k, off);
                if (ok > k) k = ok;
            }
            if (lane == 0) s_best[i & 1] = k;
        }
        __syncthreads();
        last = (int)(0xFFFFFFFFu - (unsigned)(s_best[i & 1] & 0xFFFFFFFFull)) & (N_PTS - 1);
        if (t == 0) s_sel[i] = last;
    }
    __syncthreads();
    for (int s = t; s < S_PTS; s += 1024) {
        int id = s_sel[s];
        newxyz[((size_t)b*3 + 0) * S_PTS + s] = sx[id];
        newxyz[((size_t)b*3 + 1) * S_PTS + s] = sy[id];
        newxyz[((size_t)b*3 + 2) * S_PTS + s] = sz[id];
    }
}

// ---------------------------------------------------------------- ball query (proven round 5)
__global__ __launch_bounds__(256) void ball_kernel(const float* __restrict__ xyz,
                                                   const float* __restrict__ newxyz,
                                                   int* __restrict__ ballidx) {
    int g    = blockIdx.x * 4 + (threadIdx.x >> 6);
    int lane = threadIdx.x & 63;
    int b = g >> 11, s = g & 2047;
    const float* xb = xyz + (size_t)b * 3 * N_PTS;
    float cx = newxyz[((size_t)b*3 + 0) * S_PTS + s];
    float cy = newxyz[((size_t)b*3 + 1) * S_PTS + s];
    float cz = newxyz[((size_t)b*3 + 2) * S_PTS + s];
    int* outp = ballidx + (size_t)g * K_SMP;

    int cnt = 0, first = 0;  bool have_first = false;
    for (int n0 = 0; n0 < N_PTS; n0 += 64) {
        int n = n0 + lane;
        float d = sqd(cx, cy, cz, xb[n], xb[N_PTS + n], xb[2*N_PTS + n]);
        bool in = (d <= R2);
        unsigned long long m = __ballot(in);
        if (in) {
            int pos = cnt + __popcll(m & ((1ull << lane) - 1ull));
            if (pos < K_SMP) outp[pos] = n;
        }
        if (!have_first && m != 0ull) { first = n0 + (int)__builtin_ctzll(m); have_first = true; }
        cnt += __popcll(m);
        if (cnt >= K_SMP) break;
    }
    if (cnt < K_SMP && lane < K_SMP && lane >= cnt) outp[lane] = first;
}

// ---------------------------------------------------------------- conv1 (proven round 5)
__global__ __launch_bounds__(256) void d_conv1(const float* __restrict__ xyz,
                                               const float* __restrict__ points,
                                               const float* __restrict__ newxyz,
                                               const int* __restrict__ ballidx,
                                               const float* __restrict__ w1,
                                               const float* __restrict__ b1,
                                               float* __restrict__ xbuf) {
    __shared__ float sw[64 * 9];
    __shared__ float sb[64];
    int t = threadIdx.x;
    for (int i = t; i < 576; i += 256) sw[i] = w1[i];
    if (t < 64) sb[t] = b1[t];
    __syncthreads();

    int p = blockIdx.x * 256 + t;
    int g = p >> 5, b = g >> 11, s = g & 2047;
    int idx = ballidx[p] & (N_PTS - 1);
    const float* xb = xyz    + (size_t)b * 3 * N_PTS;
    const float* pb = points + (size_t)b * 6 * N_PTS;
    float f[9];
    f[0] = xb[idx]           - newxyz[((size_t)b*3 + 0) * S_PTS + s];
    f[1] = xb[N_PTS + idx]   - newxyz[((size_t)b*3 + 1) * S_PTS + s];
    f[2] = xb[2*N_PTS + idx] - newxyz[((size_t)b*3 + 2) * S_PTS + s];
#pragma unroll
    for (int c = 0; c < 6; c++) f[3 + c] = pb[c * N_PTS + idx];

    float* row = xbuf + (size_t)p * 64;
    for (int co = 0; co < 64; co++) {
        float a = sb[co];
#pragma unroll
        for (int c = 0; c < 9; c++) a += sw[co * 9 + c] * f[c];
        row[co] = a;
    }
}

// ---------------------------------------------------------------- stats (proven round 5)
template <int C>
__global__ __launch_bounds__(256) void d_stats(const float* __restrict__ x,
                                               float* __restrict__ gstat) {
    __shared__ float ss[C], sq[C];
    int t = threadIdx.x;
    for (int i = t; i < C; i += 256) { ss[i] = 0.f; sq[i] = 0.f; }
    __syncthreads();
    int c = t & (C - 1), r0 = t / C;
    const int RPI = 256 / C;
    float s = 0.f, q = 0.f;
    size_t base = (size_t)blockIdx.x * 256;
    for (int r = r0; r < 256; r += RPI) {
        float v = x[(base + r) * C + c];
        s += v; q += v * v;
    }
    atomicAdd(&ss[c], s); atomicAdd(&sq[c], q);
    __syncthreads();
    for (int i = t; i < C; i += 256) { atomicAdd(&gstat[i], ss[i]); atomicAdd(&gstat[C + i], sq[i]); }
}

// ---------------------------------------------------------------- conv2 (proven round 6)
__global__ __launch_bounds__(256) void c2_kernel(float* __restrict__ xbuf,
                                                 const float* __restrict__ AB1,
                                                 const float* __restrict__ w2,
                                                 const float* __restrict__ b2) {
    __shared__ __align__(16) float wt[64 * 64];   // [c][co]
    __shared__ float sA[64], sB[64], sb[64];
    int t = threadIdx.x;
    for (int i = t; i < 4096; i += 256) { int co = i & 63, c = i >> 6; wt[c*64+co] = w2[co*64+c]; }
    if (t < 64) { sA[t] = AB1[t]; sB[t] = AB1[64 + t]; sb[t] = b2[t]; }
    __syncthreads();

    size_t p0 = (size_t)blockIdx.x * 512 + t, p1 = p0 + 256;
    float* r0 = xbuf + p0 * 64;
    float* r1 = xbuf + p1 * 64;

    float acc0[64], acc1[64];
#pragma unroll
    for (int co = 0; co < 64; co++) { float bv = sb[co]; acc0[co] = bv; acc1[co] = bv; }

#pragma unroll
    for (int c0 = 0; c0 < 64; c0 += 8) {
        float ya[8], yb[8];
#pragma unroll
        for (int q = 0; q < 8; q += 4) {
            float4 va = *(const float4*)(r0 + c0 + q);
            float4 vb = *(const float4*)(r1 + c0 + q);
            ya[q] = va.x; ya[q+1] = va.y; ya[q+2] = va.z; ya[q+3] = va.w;
            yb[q] = vb.x; yb[q+1] = vb.y; yb[q+2] = vb.z; yb[q+3] = vb.w;
        }
#pragma unroll
        for (int q = 0; q < 8; q++) {
            ya[q] = fmaxf(0.f, ya[q] * sA[c0+q] + sB[c0+q]);
            yb[q] = fmaxf(0.f, yb[q] * sA[c0+q] + sB[c0+q]);
        }
#pragma unroll
        for (int c = 0; c < 8; c++) {
            float fa = ya[c], fb = yb[c];
#pragma unroll
            for (int co = 0; co < 64; co += 4) {
                float4 w = *(const float4*)&wt[(c0+c)*64 + co];
                acc0[co]   += w.x * fa; acc0[co+1] += w.y * fa;
                acc0[co+2] += w.z * fa; acc0[co+3] += w.w * fa;
                acc1[co]   += w.x * fb; acc1[co+1] += w.y * fb;
                acc1[co+2] += w.z * fb; acc1[co+3] += w.w * fb;
            }
        }
    }
#pragma unroll
    for (int co = 0; co < 64; co += 4) {
        *(float4*)(r0 + co) = make_float4(acc0[co], acc0[co+1], acc0[co+2], acc0[co+3]);
        *(float4*)(r1 + co) = make_float4(acc1[co], acc1[co+1], acc1[co+2], acc1[co+3]);
    }
}

// ---------------------------------------------------------------- conv3 core (proven round 6)
#define C3_COMPUTE(ACC)                                                                    \
    int quarter = t & 3, q = t >> 2, cb = quarter * 32;                                    \
    size_t pB = (size_t)blockIdx.x * 256 + q;                                              \
    const float* r0 = xbuf + (pB +   0) * 64;                                              \
    const float* r1 = xbuf + (pB +  64) * 64;                                              \
    const float* r2 = xbuf + (pB + 128) * 64;                                              \
    const float* r3 = xbuf + (pB + 192) * 64;                                              \
    float ACC[4][32];                                                                      \
    _Pragma("unroll")                                                                      \
    for (int co = 0; co < 32; co++) {                                                      \
        float bv = sb3[cb + co];                                                           \
        ACC[0][co] = bv; ACC[1][co] = bv; ACC[2][co] = bv; ACC[3][co] = bv;                \
    }                                                                                      \
    _Pragma("unroll")                                                                      \
    for (int c0 = 0; c0 < 64; c0 += 8) {                                                   \
        float y[4][8];                                                                     \
        _Pragma("unroll")                                                                  \
        for (int qq = 0; qq < 8; qq += 4) {                                                \
            float4 v0 = *(const float4*)(r0 + c0 + qq);                                    \
            float4 v1 = *(const float4*)(r1 + c0 + qq);                                    \
            float4 v2 = *(const float4*)(r2 + c0 + qq);                                    \
            float4 v3 = *(const float4*)(r3 + c0 + qq);                                    \
            y[0][qq] = v0.x; y[0][qq+1] = v0.y; y[0][qq+2] = v0.z; y[0][qq+3] = v0.w;      \
            y[1][qq] = v1.x; y[1][qq+1] = v1.y; y[1][qq+2] = v1.z; y[1][qq+3] = v1.w;      \
            y[2][qq] = v2.x; y[2][qq+1] = v2.y; y[2][qq+2] = v2.z; y[2][qq+3] = v2.w;      \
            y[3][qq] = v3.x; y[3][qq+1] = v3.y; y[3][qq+2] = v3.z; y[3][qq+3] = v3.w;      \
        }                                                                                  \
        _Pragma("unroll")                                                                  \
        for (int qq = 0; qq < 8; qq++) {                                                   \
            float A = sA[c0+qq], Bv = sB[c0+qq];                                           \
            y[0][qq] = fmaxf(0.f, y[0][qq] * A + Bv);                                      \
            y[1][qq] = fmaxf(0.f, y[1][qq] * A + Bv);                                      \
            y[2][qq] = fmaxf(0.f, y[2][qq] * A + Bv);                                      \
            y[3][qq] = fmaxf(0.f, y[3][qq] * A + Bv);                                      \
        }                                                                                  \
        _Pragma("unroll")                                                                  \
        for (int c = 0; c < 8; c++) {                                                      \
            float f0 = y[0][c], f1 = y[1][c], f2 = y[2][c], f3 = y[3][c];                  \
            _Pragma("unroll")                                                              \
            for (int co = 0; co < 32; co += 4) {                                           \
                float4 w = *(const float4*)&wt[(c0+c)*128 + cb + co];                      \
                ACC[0][co]   += w.x * f0; ACC[0][co+1] += w.y * f0;                        \
                ACC[0][co+2] += w.z * f0; ACC[0][co+3] += w.w * f0;                        \
                ACC[1][co]   += w.x * f1; ACC[1][co+1] += w.y * f1;                        \
                ACC[1][co+2] += w.z * f1; ACC[1][co+3] += w.w * f1;                        \
                ACC[2][co]   += w.x * f2; ACC[2][co+1] += w.y * f2;                        \
                ACC[2][co+2] += w.z * f2; ACC[2][co+3] += w.w * f2;                        \
                ACC[3][co]   += w.x * f3; ACC[3][co+1] += w.y * f3;                        \
                ACC[3][co+2] += w.z * f3; ACC[3][co+3] += w.w * f3;                        \
            }                                                                              \
        }                                                                                  \
    }

__global__ __launch_bounds__(256) void c3_stats(const float* __restrict__ xbuf,
                                                const float* __restrict__ AB2,
                                                const float* __restrict__ w3,
                                                const float* __restrict__ b3,
                                                float* __restrict__ gstat) {
    __shared__ __align__(16) float wt[64 * 128];  // [c][ch] 32 KiB
    __shared__ float sA[64], sB[64], sb3[128], ss[128], sq[128];
    int t = threadIdx.x;
    for (int i = t; i < 8192; i += 256) { int ch = i & 127, c = i >> 7; wt[c*128+ch] = w3[ch*64+c]; }
    if (t < 64) { sA[t] = AB2[t]; sB[t] = AB2[64 + t]; }
    if (t < 128) { sb3[t] = b3[t]; ss[t] = 0.f; sq[t] = 0.f; }
    __syncthreads();

    C3_COMPUTE(acc)

#pragma unroll
    for (int co = 0; co < 32; co++) {
        float s  = acc[0][co] + acc[1][co] + acc[2][co] + acc[3][co];
        float qq = acc[0][co]*acc[0][co] + acc[1][co]*acc[1][co]
                 + acc[2][co]*acc[2][co] + acc[3][co]*acc[3][co];
        atomicAdd(&ss[cb + co], s);
        atomicAdd(&sq[cb + co], qq);
    }
    __syncthreads();
    if (t < 128) { atomicAdd(&gstat[t], ss[t]); atomicAdd(&gstat[128 + t], sq[t]); }
}

__global__ __launch_bounds__(256) void c3_max(const float* __restrict__ xbuf,
                                              const float* __restrict__ AB2,
                                              const float* __restrict__ w3,
                                              const float* __restrict__ b3,
                                              const float* __restrict__ AB3,
                                              float* __restrict__ out_np) {
    __shared__ __align__(16) float wt[64 * 128];
    __shared__ float sA[64], sB[64], sb3[128], sA3[128], sB3[128];
    __shared__ unsigned int smax[8][128];
    int t = threadIdx.x;
    for (int i = t; i < 8192; i += 256) { int ch = i & 127, c = i >> 7; wt[c*128+ch] = w3[ch*64+c]; }
    if (t < 64) { sA[t] = AB2[t]; sB[t] = AB2[64 + t]; }
    if (t < 128) { sb3[t] = b3[t]; sA3[t] = AB3[t]; sB3[t] = AB3[128 + t]; }
    for (int i = t; i < 1024; i += 256) smax[i >> 7][i & 127] = 0u;
    __syncthreads();

    C3_COMPUTE(acc)

    int g0 = (q >> 5);
#pragma unroll
    for (int co = 0; co < 32; co++) {
        int ch = cb + co;
        float A = sA3[ch], Bv = sB3[ch];
        float v0 = fmaxf(0.f, acc[0][co] * A + Bv);
        float v1 = fmaxf(0.f, acc[1][co] * A + Bv);
        float v2 = fmaxf(0.f, acc[2][co] * A + Bv);
        float v3 = fmaxf(0.f, acc[3][co] * A + Bv);
        atomicMax(&smax[g0    ][ch], __float_as_uint(v0));
        atomicMax(&smax[g0 + 2][ch], __float_as_uint(v1));
        atomicMax(&smax[g0 + 4][ch], __float_as_uint(v2));
        atomicMax(&smax[g0 + 6][ch], __float_as_uint(v3));
    }
    __syncthreads();
    for (int i = t; i < 1024; i += 256) {
        int g = i >> 7, ch = i & 127;
        int G = blockIdx.x * 8 + g;
        int b = G >> 11, s = G & 2047;
        out_np[((size_t)b * 128 + ch) * 2048 + s] = __uint_as_float(smax[g][ch]);
    }
}

// ---------------------------------------------------------------- fold BN
template <int C>
__global__ void finalize_kernel(const float* __restrict__ gstat,
                                const float* __restrict__ gamma,
                                const float* __restrict__ beta,
                                float* __restrict__ AB) {
    int t = threadIdx.x;
    if (t < C) {
        float mu  = gstat[t]     * CNT_INV;
        float ex2 = gstat[C + t] * CNT_INV;
        float var = ex2 - mu * mu;
        float A = gamma[t] * rsqrtf(var + 1e-5f);
        AB[t] = A; AB[C + t] = beta[t] - mu * A;
    }
}

// ---------------------------------------------------------------- launcher
extern "C" void kernel_launch(void* const* d_in, const int* in_sizes, int n_in,
                              void* d_out, int out_size, void* d_ws, size_t ws_size,
                              hipStream_t stream) {
    (void)in_sizes; (void)n_in; (void)out_size; (void)ws_size;
    const float* xyz    = (const float*)d_in[0];
    const float* points = (const float*)d_in[1];
    const float* w1 = (const float*)d_in[2],  *b1 = (const float*)d_in[3];
    const float* g1 = (const float*)d_in[4],  *be1 = (const float*)d_in[5];
    const float* w2 = (const float*)d_in[6],  *b2 = (const float*)d_in[7];
    const float* g2 = (const float*)d_in[8],  *be2 = (const float*)d_in[9];
    const float* w3 = (const float*)d_in[10], *b3 = (const float*)d_in[11];
    const float* g3 = (const float*)d_in[12], *be3 = (const float*)d_in[13];

    float* out    = (float*)d_out;                      // new_xyz (B,3,S)
    float* out_np = out + (size_t)BATCH * 3 * S_PTS;    // new_points (B,128,S)

    // ws: [0,2M) ballidx | [2M,+6K) stats/AB | [4M, 132M) xbuf (proven size)
    char*  ws      = (char*)d_ws;
    int*   ballidx = (int*)ws;
    float* gbase   = (float*)(ws + (2ull << 20));
    float* gstat1  = gbase;
    float* gstat2  = gbase + 256;
    float* gstat3  = gbase + 512;
    float* AB1     = gbase + 768;
    float* AB2     = gbase + 896;
    float* AB3     = gbase + 1024;
    float* xbuf    = (float*)(ws + (4ull << 20));

    hipMemsetAsync(gstat1, 0, 768 * sizeof(float), stream);

    fps_kernel  <<<BATCH, 1024, 0, stream>>>(xyz, out);
    ball_kernel <<<(BATCH * S_PTS) / 4, 256, 0, stream>>>(xyz, out, ballidx);
    d_conv1     <<<P_TOT / 256, 256, 0, stream>>>(xyz, points, out, ballidx, w1, b1, xbuf);
    d_stats<64> <<<P_TOT / 256, 256, 0, stream>>>(xbuf, gstat1);
    finalize_kernel<64><<<1, 64, 0, stream>>>(gstat1, g1, be1, AB1);
    c2_kernel   <<<P_TOT / 512, 256, 0, stream>>>(xbuf, AB1, w2, b2);
    d_stats<64> <<<P_TOT / 256, 256, 0, stream>>>(xbuf, gstat2);
    finalize_kernel<64><<<1, 64, 0, stream>>>(gstat2, g2, be2, AB2);
    c3_stats    <<<P_TOT / 256, 256, 0, stream>>>(xbuf, AB2, w3, b3, gstat3);
    finalize_kernel<128><<<1, 128, 0, stream>>>(gstat3, g3, be3, AB3);
    c3_max      <<<P_TOT / 256, 256, 0, stream>>>(xbuf, AB2, w3, b3, AB3, out_np);
}

// Round 8
// 3342.703 us; speedup vs baseline: 1.1852x; 1.1852x over previous
//
#include <hip/hip_runtime.h>
#include <cstdint>

#define N_PTS   8192
#define S_PTS   2048
#define K_SMP   32
#define BATCH   8
#define P_TOT   (BATCH*S_PTS*K_SMP)   /* 524288 */
#define R2      0.16f
#define CNT_INV (1.0f/524288.0f)

// Unfused: matches numpy-f32 elementwise square + sequential 3-sum.
// PROVEN r5/r6/r7 for ball query — do not change there.
__device__ __forceinline__ float sqd(float ax, float ay, float az,
                                     float bx, float by, float bz) {
    float dx = __fsub_rn(ax, bx), dy = __fsub_rn(ay, by), dz = __fsub_rn(az, bz);
    return __fadd_rn(__fadd_rn(__fmul_rn(dx, dx), __fmul_rn(dy, dy)), __fmul_rn(dz, dz));
}

// ---------------------------------------------------------------- FPS v4
// 512 thr (8 waves, 2/SIMD: latency overlap without r7's barrier blowup) x 16
// pts. fma-sqd (r4 Output0 proved selection-safe), packed float4 coords (one
// b128 broadcast/step). Reduce: per-thread fmax + rescan -> DPP row_ror
// 1/2/4/8 -> shfl_xor 16/32 -> 1 partial/wave -> ONE barrier -> all threads
// scan 8 keys. Double-buffered partials (r6-proven race-free pattern).
// Key = bits(maxval)<<32 | ~idx : max val, ties -> min idx (argmax semantics).
#define ROR_STEP(N)                                                                         \
    {                                                                                       \
        float ov = __int_as_float(__builtin_amdgcn_mov_dpp(__float_as_int(bv),              \
                                                           0x120|(N), 0xF, 0xF, true));     \
        int   oi = __builtin_amdgcn_mov_dpp(bi, 0x120|(N), 0xF, 0xF, true);                 \
        if (ov > bv || (ov == bv && oi < bi)) { bv = ov; bi = oi; }                         \
    }
#define XOR_STEP(N)                                                                         \
    {                                                                                       \
        float ov = __shfl_xor(bv, N);                                                       \
        int   oi = __shfl_xor(bi, N);                                                       \
        if (ov > bv || (ov == bv && oi < bi)) { bv = ov; bi = oi; }                         \
    }

__global__ __launch_bounds__(512) void fps_kernel(const float* __restrict__ xyz,
                                                  float* __restrict__ newxyz) {
    __shared__ float4 pts[N_PTS];                          // 128 KiB packed coords
    __shared__ unsigned long long s_part[2][8];            // per-wave partials, dbuf
    __shared__ int s_sel[S_PTS];                           // 8 KiB

    const int b = blockIdx.x, t = threadIdx.x;
    const int w = t >> 6, lane = t & 63;
    const float* xb = xyz + (size_t)b * 3 * N_PTS;
    const int base = t * 16;

    float px[16], py[16], pz[16], dist[16];
#pragma unroll
    for (int q = 0; q < 4; q++) {
        float4 vx = *(const float4*)(xb + base + 4 * q);
        float4 vy = *(const float4*)(xb + N_PTS + base + 4 * q);
        float4 vz = *(const float4*)(xb + 2 * N_PTS + base + 4 * q);
        px[4*q] = vx.x; px[4*q+1] = vx.y; px[4*q+2] = vx.z; px[4*q+3] = vx.w;
        py[4*q] = vy.x; py[4*q+1] = vy.y; py[4*q+2] = vy.z; py[4*q+3] = vy.w;
        pz[4*q] = vz.x; pz[4*q+1] = vz.y; pz[4*q+2] = vz.z; pz[4*q+3] = vz.w;
    }
#pragma unroll
    for (int j = 0; j < 16; j++) {
        pts[base+j] = make_float4(px[j], py[j], pz[j], 0.f);
        dist[j] = 1e10f;
    }
    if (t == 0) s_sel[0] = 0;
    __syncthreads();

    int last = 0;
    for (int i = 1; i < S_PTS; i++) {
        float4 L = pts[last];                     // ONE b128 broadcast read
        float lx = L.x, ly = L.y, lz = L.z;
        float bv = -1.0f;
#pragma unroll
        for (int j = 0; j < 16; j++) {
            float dx = px[j] - lx, dy = py[j] - ly, dz = pz[j] - lz;
            float d  = __fmaf_rn(dz, dz, __fmaf_rn(dy, dy, __fmul_rn(dx, dx)));
            float nd = fminf(dist[j], d);
            dist[j] = nd;
            bv = fmaxf(bv, nd);
        }
        int bi = base;
#pragma unroll
        for (int j = 15; j >= 0; j--) if (dist[j] == bv) bi = base + j;  // min j wins

        ROR_STEP(1) ROR_STEP(2) ROR_STEP(4) ROR_STEP(8)    // 16-lane row argmax
        XOR_STEP(16) XOR_STEP(32)                          // cross-row -> wave argmax
        if (lane == 0)
            s_part[i & 1][w] = ((unsigned long long)__float_as_uint(bv) << 32)
                             | (unsigned long long)(0xFFFFFFFFu - (unsigned)bi);
        __syncthreads();
        const unsigned long long* sp = s_part[i & 1];
        unsigned long long best = sp[0];
#pragma unroll
        for (int r = 1; r < 8; r++) { unsigned long long k = sp[r]; if (k > best) best = k; }
        last = (int)(0xFFFFFFFFu - (unsigned)(best & 0xFFFFFFFFull)) & (N_PTS - 1);
        if (t == 0) s_sel[i] = last;
    }
    __syncthreads();
    for (int s = t; s < S_PTS; s += 512) {
        float4 P = pts[s_sel[s]];
        newxyz[((size_t)b*3 + 0) * S_PTS + s] = P.x;
        newxyz[((size_t)b*3 + 1) * S_PTS + s] = P.y;
        newxyz[((size_t)b*3 + 2) * S_PTS + s] = P.z;
    }
}

// ---------------------------------------------------------------- ball query (proven round 5)
__global__ __launch_bounds__(256) void ball_kernel(const float* __restrict__ xyz,
                                                   const float* __restrict__ newxyz,
                                                   int* __restrict__ ballidx) {
    int g    = blockIdx.x * 4 + (threadIdx.x >> 6);
    int lane = threadIdx.x & 63;
    int b = g >> 11, s = g & 2047;
    const float* xb = xyz + (size_t)b * 3 * N_PTS;
    float cx = newxyz[((size_t)b*3 + 0) * S_PTS + s];
    float cy = newxyz[((size_t)b*3 + 1) * S_PTS + s];
    float cz = newxyz[((size_t)b*3 + 2) * S_PTS + s];
    int* outp = ballidx + (size_t)g * K_SMP;

    int cnt = 0, first = 0;  bool have_first = false;
    for (int n0 = 0; n0 < N_PTS; n0 += 64) {
        int n = n0 + lane;
        float d = sqd(cx, cy, cz, xb[n], xb[N_PTS + n], xb[2*N_PTS + n]);
        bool in = (d <= R2);
        unsigned long long m = __ballot(in);
        if (in) {
            int pos = cnt + __popcll(m & ((1ull << lane) - 1ull));
            if (pos < K_SMP) outp[pos] = n;
        }
        if (!have_first && m != 0ull) { first = n0 + (int)__builtin_ctzll(m); have_first = true; }
        cnt += __popcll(m);
        if (cnt >= K_SMP) break;
    }
    if (cnt < K_SMP && lane < K_SMP && lane >= cnt) outp[lane] = first;
}

// ---------------------------------------------------------------- conv1 (proven round 5)
__global__ __launch_bounds__(256) void d_conv1(const float* __restrict__ xyz,
                                               const float* __restrict__ points,
                                               const float* __restrict__ newxyz,
                                               const int* __restrict__ ballidx,
                                               const float* __restrict__ w1,
                                               const float* __restrict__ b1,
                                               float* __restrict__ xbuf) {
    __shared__ float sw[64 * 9];
    __shared__ float sb[64];
    int t = threadIdx.x;
    for (int i = t; i < 576; i += 256) sw[i] = w1[i];
    if (t < 64) sb[t] = b1[t];
    __syncthreads();

    int p = blockIdx.x * 256 + t;
    int g = p >> 5, b = g >> 11, s = g & 2047;
    int idx = ballidx[p] & (N_PTS - 1);
    const float* xb = xyz    + (size_t)b * 3 * N_PTS;
    const float* pb = points + (size_t)b * 6 * N_PTS;
    float f[9];
    f[0] = xb[idx]           - newxyz[((size_t)b*3 + 0) * S_PTS + s];
    f[1] = xb[N_PTS + idx]   - newxyz[((size_t)b*3 + 1) * S_PTS + s];
    f[2] = xb[2*N_PTS + idx] - newxyz[((size_t)b*3 + 2) * S_PTS + s];
#pragma unroll
    for (int c = 0; c < 6; c++) f[3 + c] = pb[c * N_PTS + idx];

    float* row = xbuf + (size_t)p * 64;
    for (int co = 0; co < 64; co++) {
        float a = sb[co];
#pragma unroll
        for (int c = 0; c < 9; c++) a += sw[co * 9 + c] * f[c];
        row[co] = a;
    }
}

// ---------------------------------------------------------------- stats (proven round 5)
template <int C>
__global__ __launch_bounds__(256) void d_stats(const float* __restrict__ x,
                                               float* __restrict__ gstat) {
    __shared__ float ss[C], sq[C];
    int t = threadIdx.x;
    for (int i = t; i < C; i += 256) { ss[i] = 0.f; sq[i] = 0.f; }
    __syncthreads();
    int c = t & (C - 1), r0 = t / C;
    const int RPI = 256 / C;
    float s = 0.f, q = 0.f;
    size_t base = (size_t)blockIdx.x * 256;
    for (int r = r0; r < 256; r += RPI) {
        float v = x[(base + r) * C + c];
        s += v; q += v * v;
    }
    atomicAdd(&ss[c], s); atomicAdd(&sq[c], q);
    __syncthreads();
    for (int i = t; i < C; i += 256) { atomicAdd(&gstat[i], ss[i]); atomicAdd(&gstat[C + i], sq[i]); }
}

// ---------------------------------------------------------------- conv2 (proven round 6)
__global__ __launch_bounds__(256) void c2_kernel(float* __restrict__ xbuf,
                                                 const float* __restrict__ AB1,
                                                 const float* __restrict__ w2,
                                                 const float* __restrict__ b2) {
    __shared__ __align__(16) float wt[64 * 64];   // [c][co]
    __shared__ float sA[64], sB[64], sb[64];
    int t = threadIdx.x;
    for (int i = t; i < 4096; i += 256) { int co = i & 63, c = i >> 6; wt[c*64+co] = w2[co*64+c]; }
    if (t < 64) { sA[t] = AB1[t]; sB[t] = AB1[64 + t]; sb[t] = b2[t]; }
    __syncthreads();

    size_t p0 = (size_t)blockIdx.x * 512 + t, p1 = p0 + 256;
    float* r0 = xbuf + p0 * 64;
    float* r1 = xbuf + p1 * 64;

    float acc0[64], acc1[64];
#pragma unroll
    for (int co = 0; co < 64; co++) { float bv = sb[co]; acc0[co] = bv; acc1[co] = bv; }

#pragma unroll
    for (int c0 = 0; c0 < 64; c0 += 8) {
        float ya[8], yb[8];
#pragma unroll
        for (int q = 0; q < 8; q += 4) {
            float4 va = *(const float4*)(r0 + c0 + q);
            float4 vb = *(const float4*)(r1 + c0 + q);
            ya[q] = va.x; ya[q+1] = va.y; ya[q+2] = va.z; ya[q+3] = va.w;
            yb[q] = vb.x; yb[q+1] = vb.y; yb[q+2] = vb.z; yb[q+3] = vb.w;
        }
#pragma unroll
        for (int q = 0; q < 8; q++) {
            ya[q] = fmaxf(0.f, ya[q] * sA[c0+q] + sB[c0+q]);
            yb[q] = fmaxf(0.f, yb[q] * sA[c0+q] + sB[c0+q]);
        }
#pragma unroll
        for (int c = 0; c < 8; c++) {
            float fa = ya[c], fb = yb[c];
#pragma unroll
            for (int co = 0; co < 64; co += 4) {
                float4 w = *(const float4*)&wt[(c0+c)*64 + co];
                acc0[co]   += w.x * fa; acc0[co+1] += w.y * fa;
                acc0[co+2] += w.z * fa; acc0[co+3] += w.w * fa;
                acc1[co]   += w.x * fb; acc1[co+1] += w.y * fb;
                acc1[co+2] += w.z * fb; acc1[co+3] += w.w * fb;
            }
        }
    }
#pragma unroll
    for (int co = 0; co < 64; co += 4) {
        *(float4*)(r0 + co) = make_float4(acc0[co], acc0[co+1], acc0[co+2], acc0[co+3]);
        *(float4*)(r1 + co) = make_float4(acc1[co], acc1[co+1], acc1[co+2], acc1[co+3]);
    }
}

// ---------------------------------------------------------------- conv3 core (proven round 6)
#define C3_COMPUTE(ACC)                                                                    \
    int quarter = t & 3, q = t >> 2, cb = quarter * 32;                                    \
    size_t pB = (size_t)blockIdx.x * 256 + q;                                              \
    const float* r0 = xbuf + (pB +   0) * 64;                                              \
    const float* r1 = xbuf + (pB +  64) * 64;                                              \
    const float* r2 = xbuf + (pB + 128) * 64;                                              \
    const float* r3 = xbuf + (pB + 192) * 64;                                              \
    float ACC[4][32];                                                                      \
    _Pragma("unroll")                                                                      \
    for (int co = 0; co < 32; co++) {                                                      \
        float bv = sb3[cb + co];                                                           \
        ACC[0][co] = bv; ACC[1][co] = bv; ACC[2][co] = bv; ACC[3][co] = bv;                \
    }                                                                                      \
    _Pragma("unroll")                                                                      \
    for (int c0 = 0; c0 < 64; c0 += 8) {                                                   \
        float y[4][8];                                                                     \
        _Pragma("unroll")                                                                  \
        for (int qq = 0; qq < 8; qq += 4) {                                                \
            float4 v0 = *(const float4*)(r0 + c0 + qq);                                    \
            float4 v1 = *(const float4*)(r1 + c0 + qq);                                    \
            float4 v2 = *(const float4*)(r2 + c0 + qq);                                    \
            float4 v3 = *(const float4*)(r3 + c0 + qq);                                    \
            y[0][qq] = v0.x; y[0][qq+1] = v0.y; y[0][qq+2] = v0.z; y[0][qq+3] = v0.w;      \
            y[1][qq] = v1.x; y[1][qq+1] = v1.y; y[1][qq+2] = v1.z; y[1][qq+3] = v1.w;      \
            y[2][qq] = v2.x; y[2][qq+1] = v2.y; y[2][qq+2] = v2.z; y[2][qq+3] = v2.w;      \
            y[3][qq] = v3.x; y[3][qq+1] = v3.y; y[3][qq+2] = v3.z; y[3][qq+3] = v3.w;      \
        }                                                                                  \
        _Pragma("unroll")                                                                  \
        for (int qq = 0; qq < 8; qq++) {                                                   \
            float A = sA[c0+qq], Bv = sB[c0+qq];                                           \
            y[0][qq] = fmaxf(0.f, y[0][qq] * A + Bv);                                      \
            y[1][qq] = fmaxf(0.f, y[1][qq] * A + Bv);                                      \
            y[2][qq] = fmaxf(0.f, y[2][qq] * A + Bv);                                      \
            y[3][qq] = fmaxf(0.f, y[3][qq] * A + Bv);                                      \
        }                                                                                  \
        _Pragma("unroll")                                                                  \
        for (int c = 0; c < 8; c++) {                                                      \
            float f0 = y[0][c], f1 = y[1][c], f2 = y[2][c], f3 = y[3][c];                  \
            _Pragma("unroll")                                                              \
            for (int co = 0; co < 32; co += 4) {                                           \
                float4 w = *(const float4*)&wt[(c0+c)*128 + cb + co];                      \
                ACC[0][co]   += w.x * f0; ACC[0][co+1] += w.y * f0;                        \
                ACC[0][co+2] += w.z * f0; ACC[0][co+3] += w.w * f0;                        \
                ACC[1][co]   += w.x * f1; ACC[1][co+1] += w.y * f1;                        \
                ACC[1][co+2] += w.z * f1; ACC[1][co+3] += w.w * f1;                        \
                ACC[2][co]   += w.x * f2; ACC[2][co+1] += w.y * f2;                        \
                ACC[2][co+2] += w.z * f2; ACC[2][co+3] += w.w * f2;                        \
                ACC[3][co]   += w.x * f3; ACC[3][co+1] += w.y * f3;                        \
                ACC[3][co+2] += w.z * f3; ACC[3][co+3] += w.w * f3;                        \
            }                                                                              \
        }                                                                                  \
    }

__global__ __launch_bounds__(256) void c3_stats(const float* __restrict__ xbuf,
                                                const float* __restrict__ AB2,
                                                const float* __restrict__ w3,
                                                const float* __restrict__ b3,
                                                float* __restrict__ gstat) {
    __shared__ __align__(16) float wt[64 * 128];  // [c][ch] 32 KiB
    __shared__ float sA[64], sB[64], sb3[128], ss[128], sq[128];
    int t = threadIdx.x;
    for (int i = t; i < 8192; i += 256) { int ch = i & 127, c = i >> 7; wt[c*128+ch] = w3[ch*64+c]; }
    if (t < 64) { sA[t] = AB2[t]; sB[t] = AB2[64 + t]; }
    if (t < 128) { sb3[t] = b3[t]; ss[t] = 0.f; sq[t] = 0.f; }
    __syncthreads();

    C3_COMPUTE(acc)

#pragma unroll
    for (int co = 0; co < 32; co++) {
        float s  = acc[0][co] + acc[1][co] + acc[2][co] + acc[3][co];
        float qq = acc[0][co]*acc[0][co] + acc[1][co]*acc[1][co]
                 + acc[2][co]*acc[2][co] + acc[3][co]*acc[3][co];
        atomicAdd(&ss[cb + co], s);
        atomicAdd(&sq[cb + co], qq);
    }
    __syncthreads();
    if (t < 128) { atomicAdd(&gstat[t], ss[t]); atomicAdd(&gstat[128 + t], sq[t]); }
}

__global__ __launch_bounds__(256) void c3_max(const float* __restrict__ xbuf,
                                              const float* __restrict__ AB2,
                                              const float* __restrict__ w3,
                                              const float* __restrict__ b3,
                                              const float* __restrict__ AB3,
                                              float* __restrict__ out_np) {
    __shared__ __align__(16) float wt[64 * 128];
    __shared__ float sA[64], sB[64], sb3[128], sA3[128], sB3[128];
    __shared__ unsigned int smax[8][128];
    int t = threadIdx.x;
    for (int i = t; i < 8192; i += 256) { int ch = i & 127, c = i >> 7; wt[c*128+ch] = w3[ch*64+c]; }
    if (t < 64) { sA[t] = AB2[t]; sB[t] = AB2[64 + t]; }
    if (t < 128) { sb3[t] = b3[t]; sA3[t] = AB3[t]; sB3[t] = AB3[128 + t]; }
    for (int i = t; i < 1024; i += 256) smax[i >> 7][i & 127] = 0u;
    __syncthreads();

    C3_COMPUTE(acc)

    int g0 = (q >> 5);
#pragma unroll
    for (int co = 0; co < 32; co++) {
        int ch = cb + co;
        float A = sA3[ch], Bv = sB3[ch];
        float v0 = fmaxf(0.f, acc[0][co] * A + Bv);
        float v1 = fmaxf(0.f, acc[1][co] * A + Bv);
        float v2 = fmaxf(0.f, acc[2][co] * A + Bv);
        float v3 = fmaxf(0.f, acc[3][co] * A + Bv);
        atomicMax(&smax[g0    ][ch], __float_as_uint(v0));
        atomicMax(&smax[g0 + 2][ch], __float_as_uint(v1));
        atomicMax(&smax[g0 + 4][ch], __float_as_uint(v2));
        atomicMax(&smax[g0 + 6][ch], __float_as_uint(v3));
    }
    __syncthreads();
    for (int i = t; i < 1024; i += 256) {
        int g = i >> 7, ch = i & 127;
        int G = blockIdx.x * 8 + g;
        int b = G >> 11, s = G & 2047;
        out_np[((size_t)b * 128 + ch) * 2048 + s] = __uint_as_float(smax[g][ch]);
    }
}

// ---------------------------------------------------------------- fold BN
template <int C>
__global__ void finalize_kernel(const float* __restrict__ gstat,
                                const float* __restrict__ gamma,
                                const float* __restrict__ beta,
                                float* __restrict__ AB) {
    int t = threadIdx.x;
    if (t < C) {
        float mu  = gstat[t]     * CNT_INV;
        float ex2 = gstat[C + t] * CNT_INV;
        float var = ex2 - mu * mu;
        float A = gamma[t] * rsqrtf(var + 1e-5f);
        AB[t] = A; AB[C + t] = beta[t] - mu * A;
    }
}

// ---------------------------------------------------------------- launcher
extern "C" void kernel_launch(void* const* d_in, const int* in_sizes, int n_in,
                              void* d_out, int out_size, void* d_ws, size_t ws_size,
                              hipStream_t stream) {
    (void)in_sizes; (void)n_in; (void)out_size; (void)ws_size;
    const float* xyz    = (const float*)d_in[0];
    const float* points = (const float*)d_in[1];
    const float* w1 = (const float*)d_in[2],  *b1 = (const float*)d_in[3];
    const float* g1 = (const float*)d_in[4],  *be1 = (const float*)d_in[5];
    const float* w2 = (const float*)d_in[6],  *b2 = (const float*)d_in[7];
    const float* g2 = (const float*)d_in[8],  *be2 = (const float*)d_in[9];
    const float* w3 = (const float*)d_in[10], *b3 = (const float*)d_in[11];
    const float* g3 = (const float*)d_in[12], *be3 = (const float*)d_in[13];

    float* out    = (float*)d_out;                      // new_xyz (B,3,S)
    float* out_np = out + (size_t)BATCH * 3 * S_PTS;    // new_points (B,128,S)

    // ws: [0,2M) ballidx | [2M,+6K) stats/AB | [4M, 132M) xbuf (proven size)
    char*  ws      = (char*)d_ws;
    int*   ballidx = (int*)ws;
    float* gbase   = (float*)(ws + (2ull << 20));
    float* gstat1  = gbase;
    float* gstat2  = gbase + 256;
    float* gstat3  = gbase + 512;
    float* AB1     = gbase + 768;
    float* AB2     = gbase + 896;
    float* AB3     = gbase + 1024;
    float* xbuf    = (float*)(ws + (4ull << 20));

    hipMemsetAsync(gstat1, 0, 768 * sizeof(float), stream);

    fps_kernel  <<<BATCH, 512, 0, stream>>>(xyz, out);
    ball_kernel <<<(BATCH * S_PTS) / 4, 256, 0, stream>>>(xyz, out, ballidx);
    d_conv1     <<<P_TOT / 256, 256, 0, stream>>>(xyz, points, out, ballidx, w1, b1, xbuf);
    d_stats<64> <<<P_TOT / 256, 256, 0, stream>>>(xbuf, gstat1);
    finalize_kernel<64><<<1, 64, 0, stream>>>(gstat1, g1, be1, AB1);
    c2_kernel   <<<P_TOT / 512, 256, 0, stream>>>(xbuf, AB1, w2, b2);
    d_stats<64> <<<P_TOT / 256, 256, 0, stream>>>(xbuf, gstat2);
    finalize_kernel<64><<<1, 64, 0, stream>>>(gstat2, g2, be2, AB2);
    c3_stats    <<<P_TOT / 256, 256, 0, stream>>>(xbuf, AB2, w3, b3, gstat3);
    finalize_kernel<128><<<1, 128, 0, stream>>>(gstat3, g3, be3, AB3);
    c3_max      <<<P_TOT / 256, 256, 0, stream>>>(xbuf, AB2, w3, b3, AB3, out_np);
}

// Round 10
// 3042.618 us; speedup vs baseline: 1.3021x; 1.0986x over previous
//
#include <hip/hip_runtime.h>
#include <cstdint>

#define N_PTS   8192
#define S_PTS   2048
#define K_SMP   32
#define BATCH   8
#define P_TOT   (BATCH*S_PTS*K_SMP)   /* 524288 */
#define R2      0.16f
#define CNT_INV (1.0f/524288.0f)

// Unfused: matches numpy-f32 elementwise square + sequential 3-sum. PROVEN (ball).
__device__ __forceinline__ float sqd(float ax, float ay, float az,
                                     float bx, float by, float bz) {
    float dx = __fsub_rn(ax, bx), dy = __fsub_rn(ay, by), dz = __fsub_rn(az, bz);
    return __fadd_rn(__fadd_rn(__fmul_rn(dx, dx), __fmul_rn(dy, dy)), __fmul_rn(dz, dz));
}

// ---------------------------------------------------------------- FPS (FROZEN r8: 2253us)
#define ROR_STEP(N)                                                                         \
    {                                                                                       \
        float ov = __int_as_float(__builtin_amdgcn_mov_dpp(__float_as_int(bv),              \
                                                           0x120|(N), 0xF, 0xF, true));     \
        int   oi = __builtin_amdgcn_mov_dpp(bi, 0x120|(N), 0xF, 0xF, true);                 \
        if (ov > bv || (ov == bv && oi < bi)) { bv = ov; bi = oi; }                         \
    }
#define XOR_STEP(N)                                                                         \
    {                                                                                       \
        float ov = __shfl_xor(bv, N);                                                       \
        int   oi = __shfl_xor(bi, N);                                                       \
        if (ov > bv || (ov == bv && oi < bi)) { bv = ov; bi = oi; }                         \
    }

__global__ __launch_bounds__(512) void fps_kernel(const float* __restrict__ xyz,
                                                  float* __restrict__ newxyz) {
    __shared__ float4 pts[N_PTS];                          // 128 KiB packed coords
    __shared__ unsigned long long s_part[2][8];            // per-wave partials, dbuf
    __shared__ int s_sel[S_PTS];                           // 8 KiB

    const int b = blockIdx.x, t = threadIdx.x;
    const int w = t >> 6, lane = t & 63;
    const float* xb = xyz + (size_t)b * 3 * N_PTS;
    const int base = t * 16;

    float px[16], py[16], pz[16], dist[16];
#pragma unroll
    for (int q = 0; q < 4; q++) {
        float4 vx = *(const float4*)(xb + base + 4 * q);
        float4 vy = *(const float4*)(xb + N_PTS + base + 4 * q);
        float4 vz = *(const float4*)(xb + 2 * N_PTS + base + 4 * q);
        px[4*q] = vx.x; px[4*q+1] = vx.y; px[4*q+2] = vx.z; px[4*q+3] = vx.w;
        py[4*q] = vy.x; py[4*q+1] = vy.y; py[4*q+2] = vy.z; py[4*q+3] = vy.w;
        pz[4*q] = vz.x; pz[4*q+1] = vz.y; pz[4*q+2] = vz.z; pz[4*q+3] = vz.w;
    }
#pragma unroll
    for (int j = 0; j < 16; j++) {
        pts[base+j] = make_float4(px[j], py[j], pz[j], 0.f);
        dist[j] = 1e10f;
    }
    if (t == 0) s_sel[0] = 0;
    __syncthreads();

    int last = 0;
    for (int i = 1; i < S_PTS; i++) {
        float4 L = pts[last];                     // ONE b128 broadcast read
        float lx = L.x, ly = L.y, lz = L.z;
        float bv = -1.0f;
#pragma unroll
        for (int j = 0; j < 16; j++) {
            float dx = px[j] - lx, dy = py[j] - ly, dz = pz[j] - lz;
            float d  = __fmaf_rn(dz, dz, __fmaf_rn(dy, dy, __fmul_rn(dx, dx)));
            float nd = fminf(dist[j], d);
            dist[j] = nd;
            bv = fmaxf(bv, nd);
        }
        int bi = base;
#pragma unroll
        for (int j = 15; j >= 0; j--) if (dist[j] == bv) bi = base + j;  // min j wins

        ROR_STEP(1) ROR_STEP(2) ROR_STEP(4) ROR_STEP(8)
        XOR_STEP(16) XOR_STEP(32)
        if (lane == 0)
            s_part[i & 1][w] = ((unsigned long long)__float_as_uint(bv) << 32)
                             | (unsigned long long)(0xFFFFFFFFu - (unsigned)bi);
        __syncthreads();
        const unsigned long long* sp = s_part[i & 1];
        unsigned long long best = sp[0];
#pragma unroll
        for (int r = 1; r < 8; r++) { unsigned long long k = sp[r]; if (k > best) best = k; }
        last = (int)(0xFFFFFFFFu - (unsigned)(best & 0xFFFFFFFFull)) & (N_PTS - 1);
        if (t == 0) s_sel[i] = last;
    }
    __syncthreads();
    for (int s = t; s < S_PTS; s += 512) {
        float4 P = pts[s_sel[s]];
        newxyz[((size_t)b*3 + 0) * S_PTS + s] = P.x;
        newxyz[((size_t)b*3 + 1) * S_PTS + s] = P.y;
        newxyz[((size_t)b*3 + 2) * S_PTS + s] = P.z;
    }
}

// ---------------------------------------------------------------- ball query (FROZEN)
__global__ __launch_bounds__(256) void ball_kernel(const float* __restrict__ xyz,
                                                   const float* __restrict__ newxyz,
                                                   int* __restrict__ ballidx) {
    int g    = blockIdx.x * 4 + (threadIdx.x >> 6);
    int lane = threadIdx.x & 63;
    int b = g >> 11, s = g & 2047;
    const float* xb = xyz + (size_t)b * 3 * N_PTS;
    float cx = newxyz[((size_t)b*3 + 0) * S_PTS + s];
    float cy = newxyz[((size_t)b*3 + 1) * S_PTS + s];
    float cz = newxyz[((size_t)b*3 + 2) * S_PTS + s];
    int* outp = ballidx + (size_t)g * K_SMP;

    int cnt = 0, first = 0;  bool have_first = false;
    for (int n0 = 0; n0 < N_PTS; n0 += 64) {
        int n = n0 + lane;
        float d = sqd(cx, cy, cz, xb[n], xb[N_PTS + n], xb[2*N_PTS + n]);
        bool in = (d <= R2);
        unsigned long long m = __ballot(in);
        if (in) {
            int pos = cnt + __popcll(m & ((1ull << lane) - 1ull));
            if (pos < K_SMP) outp[pos] = n;
        }
        if (!have_first && m != 0ull) { first = n0 + (int)__builtin_ctzll(m); have_first = true; }
        cnt += __popcll(m);
        if (cnt >= K_SMP) break;
    }
    if (cnt < K_SMP && lane < K_SMP && lane >= cnt) outp[lane] = first;
}

// ---------------------------------------------------------------- conv1 -> TRANSPOSED xT[c][P]
// Same gather+compute body as proven d_conv1; stores now coalesced
// (consecutive lanes -> consecutive p at fixed channel).
__global__ __launch_bounds__(256) void d_conv1(const float* __restrict__ xyz,
                                               const float* __restrict__ points,
                                               const float* __restrict__ newxyz,
                                               const int* __restrict__ ballidx,
                                               const float* __restrict__ w1,
                                               const float* __restrict__ b1,
                                               float* __restrict__ xT) {
    __shared__ float sw[64 * 9];
    __shared__ float sb[64];
    int t = threadIdx.x;
    for (int i = t; i < 576; i += 256) sw[i] = w1[i];
    if (t < 64) sb[t] = b1[t];
    __syncthreads();

    int p = blockIdx.x * 256 + t;
    int g = p >> 5, b = g >> 11, s = g & 2047;
    int idx = ballidx[p] & (N_PTS - 1);
    const float* xb = xyz    + (size_t)b * 3 * N_PTS;
    const float* pb = points + (size_t)b * 6 * N_PTS;
    float f[9];
    f[0] = xb[idx]           - newxyz[((size_t)b*3 + 0) * S_PTS + s];
    f[1] = xb[N_PTS + idx]   - newxyz[((size_t)b*3 + 1) * S_PTS + s];
    f[2] = xb[2*N_PTS + idx] - newxyz[((size_t)b*3 + 2) * S_PTS + s];
#pragma unroll
    for (int c = 0; c < 6; c++) f[3 + c] = pb[c * N_PTS + idx];

    for (int co = 0; co < 64; co++) {
        float a = sb[co];
#pragma unroll
        for (int c = 0; c < 9; c++) a += sw[co * 9 + c] * f[c];
        xT[(size_t)co * P_TOT + p] = a;     // coalesced
    }
}

// ---------------------------------------------------------------- channel-major stats (C=64)
// Block = (channel, slice): streams a contiguous P/8 run -> wave reduce -> atomics.
__global__ __launch_bounds__(256) void d_statsT(const float* __restrict__ xT,
                                                float* __restrict__ gstat) {
    __shared__ float ls[2];
    int t = threadIdx.x;
    if (t < 2) ls[t] = 0.f;
    __syncthreads();
    int c = blockIdx.x >> 3, sl = blockIdx.x & 7;
    const float* base = xT + (size_t)c * P_TOT + sl * 65536;
    float s = 0.f, q = 0.f;
    for (int i = t * 4; i < 65536; i += 1024) {
        float4 v = *(const float4*)(base + i);
        s += v.x + v.y + v.z + v.w;
        q += v.x*v.x + v.y*v.y + v.z*v.z + v.w*v.w;
    }
#pragma unroll
    for (int off = 1; off <= 32; off <<= 1) { s += __shfl_xor(s, off); q += __shfl_xor(q, off); }
    if ((t & 63) == 0) { atomicAdd(&ls[0], s); atomicAdd(&ls[1], q); }
    __syncthreads();
    if (t == 0) { atomicAdd(&gstat[c], ls[0]); atomicAdd(&gstat[64 + c], ls[1]); }
}

// ---------------------------------------------------------------- conv2 (body = proven c2; I/O transposed, in place)
// Thread owns positions p0,p1 (exclusive columns -> in-place safe).
__global__ __launch_bounds__(256) void c2_kernel(float* __restrict__ xT,
                                                 const float* __restrict__ AB1,
                                                 const float* __restrict__ w2,
                                                 const float* __restrict__ b2) {
    __shared__ __align__(16) float wt[64 * 64];   // [c][co]
    __shared__ float sA[64], sB[64], sb[64];
    int t = threadIdx.x;
    for (int i = t; i < 4096; i += 256) { int co = i & 63, c = i >> 6; wt[c*64+co] = w2[co*64+c]; }
    if (t < 64) { sA[t] = AB1[t]; sB[t] = AB1[64 + t]; sb[t] = b2[t]; }
    __syncthreads();

    size_t p0 = (size_t)blockIdx.x * 512 + t, p1 = p0 + 256;

    float acc0[64], acc1[64];
#pragma unroll
    for (int co = 0; co < 64; co++) { float bv = sb[co]; acc0[co] = bv; acc1[co] = bv; }

#pragma unroll
    for (int c0 = 0; c0 < 64; c0 += 8) {
        float ya[8], yb[8];
#pragma unroll
        for (int q = 0; q < 8; q++) {
            ya[q] = xT[(size_t)(c0+q) * P_TOT + p0];   // coalesced
            yb[q] = xT[(size_t)(c0+q) * P_TOT + p1];
        }
#pragma unroll
        for (int q = 0; q < 8; q++) {
            ya[q] = fmaxf(0.f, ya[q] * sA[c0+q] + sB[c0+q]);
            yb[q] = fmaxf(0.f, yb[q] * sA[c0+q] + sB[c0+q]);
        }
#pragma unroll
        for (int c = 0; c < 8; c++) {
            float fa = ya[c], fb = yb[c];
#pragma unroll
            for (int co = 0; co < 64; co += 4) {
                float4 w = *(const float4*)&wt[(c0+c)*64 + co];
                acc0[co]   += w.x * fa; acc0[co+1] += w.y * fa;
                acc0[co+2] += w.z * fa; acc0[co+3] += w.w * fa;
                acc1[co]   += w.x * fb; acc1[co+1] += w.y * fb;
                acc1[co+2] += w.z * fb; acc1[co+3] += w.w * fb;
            }
        }
    }
#pragma unroll
    for (int co = 0; co < 64; co++) {
        xT[(size_t)co * P_TOT + p0] = acc0[co];        // coalesced
        xT[(size_t)co * P_TOT + p1] = acc1[co];
    }
}

// ---------------------------------------------------------------- BN3 stats via moments:
// M = sum_p z2 z2^T (64x64), S = sum_p z2. Replaces the 8.6GF conv3-stats pass.
// 512 blocks x 4 chunks of 256 positions; z staged in LDS [pos][68]; per-thread 4x4 tile.
__global__ __launch_bounds__(256) void c3m_kernel(const float* __restrict__ xT,
                                                  const float* __restrict__ AB2,
                                                  float* __restrict__ M3,
                                                  float* __restrict__ S3) {
    __shared__ __align__(16) float zb[256][68];    // 69.6 KiB, padded
    __shared__ float sA[64], sB[64];
    int t = threadIdx.x;
    if (t < 64) { sA[t] = AB2[t]; sB[t] = AB2[64 + t]; }
    __syncthreads();

    int i0 = (t >> 4) * 4, j0 = (t & 15) * 4;
    float m00=0,m01=0,m02=0,m03=0,m10=0,m11=0,m12=0,m13=0;
    float m20=0,m21=0,m22=0,m23=0,m30=0,m31=0,m32=0,m33=0;
    float ssum = 0.f;                              // threads 192..255: channel t-192

    for (int chunk = 0; chunk < 4; chunk++) {
        size_t p = (size_t)blockIdx.x * 1024 + chunk * 256 + t;
        for (int c = 0; c < 64; c++) {
            float v = xT[(size_t)c * P_TOT + p];   // coalesced
            zb[t][c] = fmaxf(0.f, v * sA[c] + sB[c]);
        }
        __syncthreads();
        for (int r = 0; r < 256; r++) {
            float4 zi = *(const float4*)&zb[r][i0];
            float4 zj = *(const float4*)&zb[r][j0];
            m00 += zi.x*zj.x; m01 += zi.x*zj.y; m02 += zi.x*zj.z; m03 += zi.x*zj.w;
            m10 += zi.y*zj.x; m11 += zi.y*zj.y; m12 += zi.y*zj.z; m13 += zi.y*zj.w;
            m20 += zi.z*zj.x; m21 += zi.z*zj.y; m22 += zi.z*zj.z; m23 += zi.z*zj.w;
            m30 += zi.w*zj.x; m31 += zi.w*zj.y; m32 += zi.w*zj.z; m33 += zi.w*zj.w;
        }
        if (t >= 192) { int ch = t - 192; for (int r = 0; r < 256; r++) ssum += zb[r][ch]; }
        __syncthreads();
    }
    atomicAdd(&M3[(i0+0)*64 + j0+0], m00); atomicAdd(&M3[(i0+0)*64 + j0+1], m01);
    atomicAdd(&M3[(i0+0)*64 + j0+2], m02); atomicAdd(&M3[(i0+0)*64 + j0+3], m03);
    atomicAdd(&M3[(i0+1)*64 + j0+0], m10); atomicAdd(&M3[(i0+1)*64 + j0+1], m11);
    atomicAdd(&M3[(i0+1)*64 + j0+2], m12); atomicAdd(&M3[(i0+1)*64 + j0+3], m13);
    atomicAdd(&M3[(i0+2)*64 + j0+0], m20); atomicAdd(&M3[(i0+2)*64 + j0+1], m21);
    atomicAdd(&M3[(i0+2)*64 + j0+2], m22); atomicAdd(&M3[(i0+2)*64 + j0+3], m23);
    atomicAdd(&M3[(i0+3)*64 + j0+0], m30); atomicAdd(&M3[(i0+3)*64 + j0+1], m31);
    atomicAdd(&M3[(i0+3)*64 + j0+2], m32); atomicAdd(&M3[(i0+3)*64 + j0+3], m33);
    if (t >= 192) atomicAdd(&S3[t - 192], ssum);
}

// finalizeM3: gstat3[ch] = w.S + P b ; gstat3[128+ch] = wMw^T + 2b(w.S) + P b^2
__global__ void finalizeM3_kernel(const float* __restrict__ M3,
                                  const float* __restrict__ S3,
                                  const float* __restrict__ w3,
                                  const float* __restrict__ b3,
                                  float* __restrict__ gstat3) {
    __shared__ float sM[4096], sS[64];
    int t = threadIdx.x;
    for (int i = t; i < 4096; i += 128) sM[i] = M3[i];
    if (t < 64) sS[t] = S3[t];
    __syncthreads();

    float wv[64];
#pragma unroll
    for (int j = 0; j < 64; j++) wv[j] = w3[t * 64 + j];
    float b = b3[t];
    float dot = 0.f, quad = 0.f;
    for (int i = 0; i < 64; i++) {
        float di = 0.f;
        const float* Mr = &sM[i * 64];
#pragma unroll
        for (int j = 0; j < 64; j++) di += Mr[j] * wv[j];
        quad += wv[i] * di;
        dot  += wv[i] * sS[i];
    }
    gstat3[t]       = dot + (float)P_TOT * b;
    gstat3[128 + t] = quad + 2.f * b * dot + (float)P_TOT * b * b;
}

// ---------------------------------------------------------------- conv3 + BN3 + relu + max (body = proven c3_max; loads transposed)
__global__ __launch_bounds__(256) void c3_max(const float* __restrict__ xT,
                                              const float* __restrict__ AB2,
                                              const float* __restrict__ w3,
                                              const float* __restrict__ b3,
                                              const float* __restrict__ AB3,
                                              float* __restrict__ out_np) {
    __shared__ __align__(16) float wt[64 * 128];
    __shared__ float sA[64], sB[64], sb3[128], sA3[128], sB3[128];
    __shared__ unsigned int smax[8][128];
    int t = threadIdx.x;
    for (int i = t; i < 8192; i += 256) { int ch = i & 127, c = i >> 7; wt[c*128+ch] = w3[ch*64+c]; }
    if (t < 64) { sA[t] = AB2[t]; sB[t] = AB2[64 + t]; }
    if (t < 128) { sb3[t] = b3[t]; sA3[t] = AB3[t]; sB3[t] = AB3[128 + t]; }
    for (int i = t; i < 1024; i += 256) smax[i >> 7][i & 127] = 0u;
    __syncthreads();

    int quarter = t & 3, q = t >> 2, cb = quarter * 32;
    size_t pB = (size_t)blockIdx.x * 256 + q;

    float acc[4][32];
#pragma unroll
    for (int co = 0; co < 32; co++) {
        float bv = sb3[cb + co];
        acc[0][co] = bv; acc[1][co] = bv; acc[2][co] = bv; acc[3][co] = bv;
    }
#pragma unroll
    for (int c0 = 0; c0 < 64; c0 += 8) {
        float y[4][8];
#pragma unroll
        for (int qq = 0; qq < 8; qq++) {
            const float* col = xT + (size_t)(c0+qq) * P_TOT + pB;
            y[0][qq] = col[0];          // coalesced across lanes (same c, p contiguous)
            y[1][qq] = col[64];
            y[2][qq] = col[128];
            y[3][qq] = col[192];
        }
#pragma unroll
        for (int qq = 0; qq < 8; qq++) {
            float A = sA[c0+qq], Bv = sB[c0+qq];
            y[0][qq] = fmaxf(0.f, y[0][qq] * A + Bv);
            y[1][qq] = fmaxf(0.f, y[1][qq] * A + Bv);
            y[2][qq] = fmaxf(0.f, y[2][qq] * A + Bv);
            y[3][qq] = fmaxf(0.f, y[3][qq] * A + Bv);
        }
#pragma unroll
        for (int c = 0; c < 8; c++) {
            float f0 = y[0][c], f1 = y[1][c], f2 = y[2][c], f3 = y[3][c];
#pragma unroll
            for (int co = 0; co < 32; co += 4) {
                float4 w = *(const float4*)&wt[(c0+c)*128 + cb + co];
                acc[0][co]   += w.x * f0; acc[0][co+1] += w.y * f0;
                acc[0][co+2] += w.z * f0; acc[0][co+3] += w.w * f0;
                acc[1][co]   += w.x * f1; acc[1][co+1] += w.y * f1;
                acc[1][co+2] += w.z * f1; acc[1][co+3] += w.w * f1;
                acc[2][co]   += w.x * f2; acc[2][co+1] += w.y * f2;
                acc[2][co+2] += w.z * f2; acc[2][co+3] += w.w * f2;
                acc[3][co]   += w.x * f3; acc[3][co+1] += w.y * f3;
                acc[3][co+2] += w.z * f3; acc[3][co+3] += w.w * f3;
            }
        }
    }
    int g0 = (q >> 5);
#pragma unroll
    for (int co = 0; co < 32; co++) {
        int ch = cb + co;
        float A = sA3[ch], Bv = sB3[ch];
        float v0 = fmaxf(0.f, acc[0][co] * A + Bv);
        float v1 = fmaxf(0.f, acc[1][co] * A + Bv);
        float v2 = fmaxf(0.f, acc[2][co] * A + Bv);
        float v3 = fmaxf(0.f, acc[3][co] * A + Bv);
        atomicMax(&smax[g0    ][ch], __float_as_uint(v0));
        atomicMax(&smax[g0 + 2][ch], __float_as_uint(v1));
        atomicMax(&smax[g0 + 4][ch], __float_as_uint(v2));
        atomicMax(&smax[g0 + 6][ch], __float_as_uint(v3));
    }
    __syncthreads();
    for (int i = t; i < 1024; i += 256) {
        int g = i >> 7, ch = i & 127;
        int G = blockIdx.x * 8 + g;
        int b = G >> 11, s = G & 2047;
        out_np[((size_t)b * 128 + ch) * 2048 + s] = __uint_as_float(smax[g][ch]);
    }
}

// ---------------------------------------------------------------- fold BN (FROZEN)
template <int C>
__global__ void finalize_kernel(const float* __restrict__ gstat,
                                const float* __restrict__ gamma,
                                const float* __restrict__ beta,
                                float* __restrict__ AB) {
    int t = threadIdx.x;
    if (t < C) {
        float mu  = gstat[t]     * CNT_INV;
        float ex2 = gstat[C + t] * CNT_INV;
        float var = ex2 - mu * mu;
        float A = gamma[t] * rsqrtf(var + 1e-5f);
        AB[t] = A; AB[C + t] = beta[t] - mu * A;
    }
}

// ---------------------------------------------------------------- launcher
extern "C" void kernel_launch(void* const* d_in, const int* in_sizes, int n_in,
                              void* d_out, int out_size, void* d_ws, size_t ws_size,
                              hipStream_t stream) {
    (void)in_sizes; (void)n_in; (void)out_size; (void)ws_size;
    const float* xyz    = (const float*)d_in[0];
    const float* points = (const float*)d_in[1];
    const float* w1 = (const float*)d_in[2],  *b1 = (const float*)d_in[3];
    const float* g1 = (const float*)d_in[4],  *be1 = (const float*)d_in[5];
    const float* w2 = (const float*)d_in[6],  *b2 = (const float*)d_in[7];
    const float* g2 = (const float*)d_in[8],  *be2 = (const float*)d_in[9];
    const float* w3 = (const float*)d_in[10], *b3 = (const float*)d_in[11];
    const float* g3 = (const float*)d_in[12], *be3 = (const float*)d_in[13];

    float* out    = (float*)d_out;                      // new_xyz (B,3,S)
    float* out_np = out + (size_t)BATCH * 3 * S_PTS;    // new_points (B,128,S)

    // ws: [0,2M) ballidx | [2M,+22K) stats/AB/M | [4M, 132M) xT channel-major
    char*  ws      = (char*)d_ws;
    int*   ballidx = (int*)ws;
    float* gbase   = (float*)(ws + (2ull << 20));
    float* gstat1  = gbase;            // 256
    float* gstat2  = gbase + 256;      // 256
    float* gstat3  = gbase + 512;      // 256
    float* AB1     = gbase + 768;      // 128
    float* AB2     = gbase + 896;      // 128
    float* AB3     = gbase + 1024;     // 256
    float* M3      = gbase + 1280;     // 4096
    float* S3      = gbase + 5376;     // 64
    float* xT      = (float*)(ws + (4ull << 20));

    hipMemsetAsync(gbase, 0, 5440 * sizeof(float), stream);

    fps_kernel  <<<BATCH, 512, 0, stream>>>(xyz, out);
    ball_kernel <<<(BATCH * S_PTS) / 4, 256, 0, stream>>>(xyz, out, ballidx);
    d_conv1     <<<P_TOT / 256, 256, 0, stream>>>(xyz, points, out, ballidx, w1, b1, xT);
    d_statsT    <<<512, 256, 0, stream>>>(xT, gstat1);
    finalize_kernel<64><<<1, 64, 0, stream>>>(gstat1, g1, be1, AB1);
    c2_kernel   <<<P_TOT / 512, 256, 0, stream>>>(xT, AB1, w2, b2);
    d_statsT    <<<512, 256, 0, stream>>>(xT, gstat2);
    finalize_kernel<64><<<1, 64, 0, stream>>>(gstat2, g2, be2, AB2);
    c3m_kernel  <<<512, 256, 0, stream>>>(xT, AB2, M3, S3);
    finalizeM3_kernel<<<1, 128, 0, stream>>>(M3, S3, w3, b3, gstat3);
    finalize_kernel<128><<<1, 128, 0, stream>>>(gstat3, g3, be3, AB3);
    c3_max      <<<P_TOT / 256, 256, 0, stream>>>(xT, AB2, w3, b3, AB3, out_np);
}